// Round 9
// baseline (354.836 us; speedup 1.0000x reference)
//
#include <hip/hip_runtime.h>
#include <hip/hip_bf16.h>

#define T_ 1024
#define NB 4
#define E_ 256
#define H_ 8
#define D_ 32
#define E3 768
#define NBLK 512u

typedef __attribute__((ext_vector_type(4))) short v4s;
typedef __attribute__((ext_vector_type(8))) short v8s;
typedef __attribute__((ext_vector_type(4))) float v4f;

// hardware exp2 (v_exp_f32). __exp2f collides with a glibc math.h symbol.
#define EXP2F(x) __builtin_amdgcn_exp2f(x)

// round-to-nearest-even fp32 -> bf16 bits (scalar path, epilogues)
__device__ __forceinline__ unsigned short f2bf(float x) {
    union { float f; unsigned int u; } v; v.f = x;
    unsigned int r = v.u + 0x7fffu + ((v.u >> 16) & 1u);
    return (unsigned short)(r >> 16);
}
// v_cvt_pk_bf16_f32: 2 fp32 -> packed 2x bf16 (RNE), one instruction.
__device__ __forceinline__ unsigned int cvtpk(float lo, float hi) {
    unsigned int r;
    asm("v_cvt_pk_bf16_f32 %0, %1, %2" : "=v"(r) : "v"(lo), "v"(hi));
    return r;
}

// Manual grid barrier, R24 fix of the R20 perf bug. R20 passed CORRECTNESS
// with this fence pattern but its poll loop used atomicAdd(cnt,0) -- a
// device-scope RMW from 512 block-leaders hammering one cacheline, which
// serializes (~90us/barrier, measured R5: fused 276us vs ~89us chain).
// Fix: poll with a device-scope atomic LOAD (no RMW, coherent read) +
// s_sleep backoff. Arrive unchanged (release RMW). Fences unchanged.
__device__ __forceinline__ void grid_barrier(unsigned int* cnt) {
    __syncthreads();                 // all waves' stores complete (vmcnt drain)
    __threadfence();                 // L2 writeback to device coherence point
    if (threadIdx.x == 0) {
        __hip_atomic_fetch_add(cnt, 1u, __ATOMIC_RELEASE, __HIP_MEMORY_SCOPE_AGENT);
        while (__hip_atomic_load(cnt, __ATOMIC_ACQUIRE, __HIP_MEMORY_SCOPE_AGENT) < NBLK)
            __builtin_amdgcn_s_sleep(8);
    }
    __syncthreads();
    __threadfence();                 // invalidate stale local caches before reads
}

#define KMUL   0.2550343f    // (1/sqrt(32)) * log2(e)
#define SHIFTL 11.5415603f   // 8 * log2(e)

// ---------------------------------------------------------------------------
// Kernel P: prep (verbatim R20). blocks 0..255: weight transpose fp32->bf16.
// blocks 256..319: RoPE tables. Block 0 zeroes the barrier counters.
// ---------------------------------------------------------------------------
__global__ __launch_bounds__(256) void prep_kernel(
    const float* __restrict__ w_attn, const float* __restrict__ w_proj,
    unsigned short* __restrict__ WT, unsigned short* __restrict__ WPT,
    float* __restrict__ ctab, float* __restrict__ stab,
    unsigned int* __restrict__ cnt)
{
    const int blk = blockIdx.x;
    if (blk == 0 && threadIdx.x < 8) cnt[threadIdx.x] = 0u;
    if (blk < 256) {
        __shared__ float tile[32][33];
        const int bx = blk & 31, by = blk >> 5;
        const float* src; unsigned short* dst; int N, n0;
        if (bx < 24) { src = w_attn; dst = WT;  N = 768; n0 = bx * 32; }
        else         { src = w_proj; dst = WPT; N = 256; n0 = (bx - 24) * 32; }
        const int k0 = by * 32;
        const int xx = threadIdx.x & 31, y4 = (threadIdx.x >> 5) * 4;
        #pragma unroll
        for (int i = 0; i < 4; ++i)
            tile[y4 + i][xx] = src[(size_t)(k0 + y4 + i) * N + n0 + xx];
        __syncthreads();
        #pragma unroll
        for (int i = 0; i < 4; ++i)
            dst[(size_t)(n0 + y4 + i) * 256 + k0 + xx] = f2bf(tile[xx][y4 + i]);
    } else {
        // RoPE tables: 64 blocks x 256 = 16384 entries
        const int idx = (blk - 256) * 256 + threadIdx.x;
        const int t = idx >> 4, jj = idx & 15;
        const float invf = __expf(-(float)jj * 0.5756462732485115f);  // 10000^(-jj/16)
        float s, c;
        sincosf((float)t * invf, &s, &c);
        ctab[idx] = c;
        stab[idx] = s;
    }
}

// ---------------------------------------------------------------------------
// R24: fused qkv -> attn -> proj (verbatim R20 phase bodies -- R20 PASSED
// correctness at these exact bits), manual grid barriers with the fixed
// load-poll. grid 512 x 256, __launch_bounds__(256,2) = 2 blocks/CU
// co-resident by construction.
// ---------------------------------------------------------------------------
__global__ __launch_bounds__(256, 2) void fused_kernel(
    const float* __restrict__ x,
    const float* __restrict__ b_attn, const float* __restrict__ b_proj,
    const unsigned short* __restrict__ WT, const unsigned short* __restrict__ WPT,
    const float* __restrict__ ctab, const float* __restrict__ stab,
    unsigned short* __restrict__ Qb, unsigned short* __restrict__ Kb,
    unsigned short* __restrict__ VW, unsigned short* __restrict__ Ob,
    unsigned int* __restrict__ cnt,
    float* __restrict__ out)
{
    const int bx  = blockIdx.x;          // 0..511
    const int tid = threadIdx.x;
    const int wsb  = tid >> 6;
    const int lane = tid & 63;
    const int g = lane >> 4, c = lane & 15;

    // ---------------- Phase 1: qkv ----------------
    // row = bx & 127 (blocks bx, bx+128.. differ by 0 mod 8 -> same XCD ->
    // x rows shared via that XCD's L2); col-groups 3*(bx>>7) .. +2.
    {
        const int row = bx & 127, cg0 = (bx >> 7) * 3;
        const int m0 = row * 64 + wsb * 16;
        const int bn = m0 >> 10;
        const int b  = bn >> 2, nidx = bn & 3;
        const int t_base = m0 & 1023;

        const float* xrow = x + ((size_t)(b * T_ + t_base + c) * NB + nidx) * E_;

        v4f acc[12];
        #pragma unroll
        for (int i = 0; i < 12; ++i) acc[i] = (v4f){0.f, 0.f, 0.f, 0.f};

        #pragma unroll
        for (int k0 = 0; k0 < 256; k0 += 32) {
            float4 f0 = *(const float4*)(xrow + k0 + 8 * g);
            float4 f1 = *(const float4*)(xrow + k0 + 8 * g + 4);
            union { v8s v; uint4 u; } af;
            af.u.x = cvtpk(f0.x, f0.y);
            af.u.y = cvtpk(f0.z, f0.w);
            af.u.z = cvtpk(f1.x, f1.y);
            af.u.w = cvtpk(f1.z, f1.w);
            #pragma unroll
            for (int cc = 0; cc < 3; ++cc) {
                const int n0 = (cg0 + cc) * 64;
                #pragma unroll
                for (int tt = 0; tt < 4; ++tt) {
                    v8s bfrag = *(const v8s*)(WT + (size_t)(n0 + tt * 16 + c) * 256 + k0 + 8 * g);
                    acc[cc * 4 + tt] = __builtin_amdgcn_mfma_f32_16x16x32_bf16(af.v, bfrag, acc[cc * 4 + tt], 0, 0, 0);
                }
            }
        }

        float sn[4], cs[4];
        #pragma unroll
        for (int r = 0; r < 4; ++r) {
            const int ti = (t_base + 4 * g + r) * 16 + c;
            cs[r] = ctab[ti];
            sn[r] = stab[ti];
        }

        #pragma unroll
        for (int cc = 0; cc < 3; ++cc) {
            const int n0 = (cg0 + cc) * 64;
            const int type = n0 >> 8;          // 0=q 1=k 2=v
            const int nl0  = n0 & 255;
            float bias[4];
            #pragma unroll
            for (int tt = 0; tt < 4; ++tt) bias[tt] = b_attn[n0 + tt * 16 + c];

            if (type <= 1) {
                unsigned short* Dst = (type == 0) ? Qb : Kb;
                #pragma unroll
                for (int tt = 0; tt < 4; ++tt) {
                    const int n_l = nl0 + tt * 16;
                    const int h = n_l >> 5, d = (n_l & 31) + c;
                    const int bh = bn * 8 + h;
                    const float sgn = (tt & 1) ? 1.f : -1.f;
                    const int  ptt = tt ^ 1;
                    #pragma unroll
                    for (int r = 0; r < 4; ++r) {
                        float v0 = acc[cc * 4 + tt][r] + bias[tt];
                        float v1 = acc[cc * 4 + ptt][r] + bias[ptt];
                        float o  = v0 * cs[r] + sgn * v1 * sn[r];
                        int   t  = t_base + 4 * g + r;
                        Dst[((size_t)bh * T_ + t) * D_ + d] = f2bf(o);
                    }
                }
            } else {
                const int wv_ = t_base >> 5;               // s-window
                const int tw  = (t_base & 31) + 4 * g;     // t within window
                const int pos0 = ((tw >> 4) & 1) * 4 + ((tw >> 2) & 3) * 8;
                #pragma unroll
                for (int tt = 0; tt < 4; ++tt) {
                    const int n_l = nl0 + tt * 16;
                    const int h = n_l >> 5, d = (n_l & 31) + c;
                    const int bh = bn * 8 + h;
                    ushort4 pk;
                    pk.x = f2bf(acc[cc * 4 + tt][0] + bias[tt]);
                    pk.y = f2bf(acc[cc * 4 + tt][1] + bias[tt]);
                    pk.z = f2bf(acc[cc * 4 + tt][2] + bias[tt]);
                    pk.w = f2bf(acc[cc * 4 + tt][3] + bias[tt]);
                    *(ushort4*)(VW + (((size_t)bh * 32 + wv_) * 32 + d) * 32 + pos0) = pk;
                }
            }
        }
    }

    grid_barrier(cnt + 0);

    // ---------------- Phase 2: attention (verbatim R18/R20) ----------------
    {
        const int wv = wsb;
        const int bh = bx & 63;         // id%8 = bh%8 -> same-bh blocks same XCD
        const int k  = bx >> 6;

        const int qts[2] = { k + 8 * wv, k + 56 - 8 * wv };
        const int lim1 = qts[1] >> 1;

        v8s qf[2];
        #pragma unroll
        for (int j = 0; j < 2; ++j)
            qf[j] = *(const v8s*)(Qb + ((size_t)bh * T_ + qts[j] * 16 + c) * D_ + 8 * g);

        v4f o0[2], o1[2];
        float ll[2];
        #pragma unroll
        for (int j = 0; j < 2; ++j) {
            o0[j] = (v4f){0.f, 0.f, 0.f, 0.f};
            o1[j] = (v4f){0.f, 0.f, 0.f, 0.f};
            ll[j] = 0.f;
        }

        const unsigned short* Ksrc = Kb + (size_t)bh * T_ * D_;    // [t][d], 64KB
        const unsigned short* Vsrc = VW + (size_t)bh * 32 * 1024;  // [w][d][32] interleaved

        const int koff = c * 32 + 8 * g;
        const int voff = c * 32 + 8 * g;

        v8s kA_n  = *(const v8s*)(Ksrc + koff);
        v8s kB_n  = *(const v8s*)(Ksrc + 512 + koff);
        v8s vf0_n = *(const v8s*)(Vsrc + voff);
        v8s vf1_n = *(const v8s*)(Vsrc + 512 + voff);

        for (int w = 0; w <= lim1; ++w) {
            v8s kfA = kA_n, kfB = kB_n;
            v8s vf0 = vf0_n, vf1 = vf1_n;
            if (w < lim1) {                         // wave-uniform branch
                const unsigned short* kp = Ksrc + (size_t)(w + 1) * 1024;
                const unsigned short* vp = Vsrc + (size_t)(w + 1) * 1024;
                kA_n  = *(const v8s*)(kp + koff);
                kB_n  = *(const v8s*)(kp + 512 + koff);
                vf0_n = *(const v8s*)(vp + voff);
                vf1_n = *(const v8s*)(vp + 512 + voff);
            }

            const int s0 = w * 32;
            #pragma unroll
            for (int j = 0; j < 2; ++j) {
                const int qt  = qts[j];
                const int lim = qt >> 1;
                if (lim < w) continue;          // wave-uniform
                const int q = qt * 16 + c;

                v4f zero = {0.f, 0.f, 0.f, 0.f};
                v4f sA = __builtin_amdgcn_mfma_f32_16x16x32_bf16(kfA, qf[j], zero, 0, 0, 0);
                v4f sB = __builtin_amdgcn_mfma_f32_16x16x32_bf16(kfB, qf[j], zero, 0, 0, 0);

                const bool diag = (lim == w);
                float p[8];
                #pragma unroll
                for (int r = 0; r < 4; ++r) {
                    float pa = EXP2F(fmaf(sA[r], KMUL, -SHIFTL));
                    float pb = EXP2F(fmaf(sB[r], KMUL, -SHIFTL));
                    if (diag) {
                        if (s0 + 4 * g + r > q)      pa = 0.f;
                        if (s0 + 16 + 4 * g + r > q) pb = 0.f;
                    }
                    p[r] = pa; p[4 + r] = pb;
                    ll[j] += pa + pb;
                }
                union { v8s v; uint4 u; } pu;
                pu.u.x = cvtpk(p[0], p[1]);
                pu.u.y = cvtpk(p[2], p[3]);
                pu.u.z = cvtpk(p[4], p[5]);
                pu.u.w = cvtpk(p[6], p[7]);
                o0[j] = __builtin_amdgcn_mfma_f32_16x16x32_bf16(pu.v, vf0, o0[j], 0, 0, 0);
                o1[j] = __builtin_amdgcn_mfma_f32_16x16x32_bf16(pu.v, vf1, o1[j], 0, 0, 0);
            }
        }

        const int bn = bh >> 3, h = bh & 7;
        #pragma unroll
        for (int j = 0; j < 2; ++j) {
            float l_s = ll[j];
            l_s += __shfl_xor(l_s, 16, 64);
            l_s += __shfl_xor(l_s, 32, 64);
            float linv = 1.0f / l_s;
            float lr[4];
            #pragma unroll
            for (int r = 0; r < 4; ++r) lr[r] = __shfl(linv, 4 * g + r, 64);
            const int q0 = qts[j] * 16;
            #pragma unroll
            for (int r = 0; r < 4; ++r) {
                unsigned short* Orow = Ob + ((size_t)bn * T_ + q0 + 4 * g + r) * E_ + h * D_;
                Orow[c]      = f2bf(o0[j][r] * lr[r]);
                Orow[16 + c] = f2bf(o1[j][r] * lr[r]);
            }
        }
    }

    grid_barrier(cnt + 1);

    // ---------------- Phase 3: proj (verbatim R18/R20) ----------------
    {
        const int row = bx & 127, coly = bx >> 7;
        const int m0 = row * 64 + wsb * 16;
        const int n0 = coly * 64;
        const int bn = m0 >> 10;
        const int b  = bn >> 2, nidx = bn & 3;
        const int t_base = m0 & 1023;

        const unsigned short* arow = Ob + ((size_t)bn * T_ + t_base + c) * E_;

        v4f acc[4];
        #pragma unroll
        for (int tt = 0; tt < 4; ++tt) acc[tt] = (v4f){0.f, 0.f, 0.f, 0.f};

        #pragma unroll
        for (int s = 0; s < 8; ++s) {
            v8s afrag = *(const v8s*)(arow + s * 32 + 8 * g);
            #pragma unroll
            for (int tt = 0; tt < 4; ++tt) {
                v8s bfrag = *(const v8s*)(WPT + (size_t)(n0 + tt * 16 + c) * 256 + s * 32 + 8 * g);
                acc[tt] = __builtin_amdgcn_mfma_f32_16x16x32_bf16(afrag, bfrag, acc[tt], 0, 0, 0);
            }
        }

        #pragma unroll
        for (int tt = 0; tt < 4; ++tt) {
            const int n = n0 + tt * 16 + c;
            const float bp = b_proj[n];
            #pragma unroll
            for (int r = 0; r < 4; ++r) {
                const int t = t_base + 4 * g + r;
                out[((size_t)(b * T_ + t) * NB + nidx) * E_ + n] = acc[tt][r] + bp;
            }
        }
    }
}

// ---------------------------------------------------------------------------
extern "C" void kernel_launch(void* const* d_in, const int* in_sizes, int n_in,
                              void* d_out, int out_size, void* d_ws, size_t ws_size,
                              hipStream_t stream)
{
    const float* x      = (const float*)d_in[0];
    const float* w_attn = (const float*)d_in[1];
    const float* b_attn = (const float*)d_in[2];
    const float* w_proj = (const float*)d_in[3];
    const float* b_proj = (const float*)d_in[4];
    float* out = (float*)d_out;

    // ws (ushort units): Qb/Kb/VW/Ob 2M each; WT 768*256; WPT 256*256;
    // fp32 RoPE tables (16K each); then 8 barrier counters.
    unsigned short* Qb  = (unsigned short*)d_ws;
    unsigned short* Kb  = Qb + 2097152;
    unsigned short* VW  = Kb + 2097152;
    unsigned short* Ob  = VW + 2097152;
    unsigned short* WT  = Ob + 2097152;
    unsigned short* WPT = WT + 196608;
    float* ctab = (float*)(WPT + 65536);
    float* stab = ctab + 16384;
    unsigned int* cnt = (unsigned int*)(stab + 16384);

    prep_kernel<<<320, 256, 0, stream>>>(w_attn, w_proj, WT, WPT, ctab, stab, cnt);
    fused_kernel<<<512, 256, 0, stream>>>(x, b_attn, b_proj, WT, WPT, ctab, stab,
                                          Qb, Kb, VW, Ob, cnt, out);
}

// Round 10
// 110.057 us; speedup vs baseline: 3.2241x; 3.2241x over previous
//
#include <hip/hip_runtime.h>
#include <hip/hip_bf16.h>

#define T_ 1024
#define NB 4
#define E_ 256
#define H_ 8
#define D_ 32
#define E3 768

typedef __attribute__((ext_vector_type(8))) short v8s;
typedef __attribute__((ext_vector_type(4))) float v4f;

// hardware exp2 (v_exp_f32). __exp2f collides with a glibc math.h symbol.
#define EXP2F(x) __builtin_amdgcn_exp2f(x)

// round-to-nearest-even fp32 -> bf16 bits (scalar path, epilogues)
__device__ __forceinline__ unsigned short f2bf(float x) {
    union { float f; unsigned int u; } v; v.f = x;
    unsigned int r = v.u + 0x7fffu + ((v.u >> 16) & 1u);
    return (unsigned short)(r >> 16);
}
// v_cvt_pk_bf16_f32: 2 fp32 -> packed 2x bf16 (RNE), one instruction.
// Identical rounding to f2bf.
__device__ __forceinline__ unsigned int cvtpk(float lo, float hi) {
    unsigned int r;
    asm("v_cvt_pk_bf16_f32 %0, %1, %2" : "=v"(r) : "v"(lo), "v"(hi));
    return r;
}

#define KMUL   0.2550343f    // (1/sqrt(32)) * log2(e)
#define SHIFTL 11.5415603f   // 8 * log2(e)

// ---------------------------------------------------------------------------
// R25: 3-kernel chain -- prep DELETED. R24 proved software grid barriers
// cost ~100us each regardless of poll mechanism (fusion closed); the last
// structural lever is kernel count. Each qkv/proj block now builds its own
// 64-col bf16 weight slice via a block-local LDS transpose (coalesced
// float4 global reads + f2bf -- the exact prep mechanism, made per-block),
// and RoPE sin/cos is computed inline with the bit-identical formula the
// table used (__expf(-c*ln(10000)/16), sincosf(t*invf), jj=c).
// attn is byte-verbatim R18 (131.2us last-known-good).
// LDS [64][264]: pad 264 -> row stride 528B = 33*16B (v8s reads stay 16B-
// aligned); read banks: start dword 132n%32=4n -> lanes c,c+8 share 4 banks
// = 2-way (free, m136). Write conflicts (8-way ushort) only in the 16-pass
// transpose prologue -- negligible.
// ---------------------------------------------------------------------------

// Kernel A: qkv = x @ w_attn + b_attn via MFMA, fused RoPE + split stores.
// grid (128 row, 12 col) row-fast, block 256 (4 waves x 16 rows). R18 body;
// B-fragments from block-local LDS slice instead of global WT.
__global__ __launch_bounds__(256) void qkv_mfma_kernel(
    const float* __restrict__ x,
    const float* __restrict__ w_attn,
    const float* __restrict__ b_attn,
    unsigned short* __restrict__ Qb, unsigned short* __restrict__ Kb,
    unsigned short* __restrict__ VW)
{
    __shared__ unsigned short WTs[64][264];   // [n_local][k] bf16, padded

    const int tid  = threadIdx.x;
    const int wsb  = tid >> 6;
    const int lane = tid & 63;
    const int g = lane >> 4, c = lane & 15;
    const int m0 = blockIdx.x * 64 + wsb * 16;  // wave's row base (bn,t)
    const int n0 = blockIdx.y * 64;             // col base
    const int bn = m0 >> 10;                    // uniform per block
    const int b  = bn >> 2, nidx = bn & 3;
    const int t_base = m0 & 1023;

    // ---- per-block weight transpose: w_attn[k][n0+nl] -> WTs[nl][k] ----
    {
        const int c4 = (tid & 15) * 4;   // n_local base (coalesced: 16 lanes
        const int kr = tid >> 4;         //  cover 64 consecutive floats)
        #pragma unroll
        for (int p = 0; p < 16; ++p) {
            const int k = p * 16 + kr;
            float4 w4 = *(const float4*)(w_attn + (size_t)k * E3 + n0 + c4);
            WTs[c4 + 0][k] = f2bf(w4.x);
            WTs[c4 + 1][k] = f2bf(w4.y);
            WTs[c4 + 2][k] = f2bf(w4.z);
            WTs[c4 + 3][k] = f2bf(w4.w);
        }
    }
    __syncthreads();

    const float* xrow = x + ((size_t)(b * T_ + t_base + c) * NB + nidx) * E_;

    v4f acc[4];
    #pragma unroll
    for (int tt = 0; tt < 4; ++tt) acc[tt] = (v4f){0.f, 0.f, 0.f, 0.f};

    #pragma unroll
    for (int k0 = 0; k0 < 256; k0 += 32) {
        float4 f0 = *(const float4*)(xrow + k0 + 8 * g);
        float4 f1 = *(const float4*)(xrow + k0 + 8 * g + 4);
        union { v8s v; uint4 u; } af;
        af.u.x = cvtpk(f0.x, f0.y);
        af.u.y = cvtpk(f0.z, f0.w);
        af.u.z = cvtpk(f1.x, f1.y);
        af.u.w = cvtpk(f1.z, f1.w);
        #pragma unroll
        for (int tt = 0; tt < 4; ++tt) {
            v8s bfrag = *(const v8s*)(&WTs[tt * 16 + c][k0 + 8 * g]);
            acc[tt] = __builtin_amdgcn_mfma_f32_16x16x32_bf16(af.v, bfrag, acc[tt], 0, 0, 0);
        }
    }

    float bias[4];
    #pragma unroll
    for (int tt = 0; tt < 4; ++tt) bias[tt] = b_attn[n0 + tt * 16 + c];

    const int type = n0 >> 8;          // 0=q 1=k 2=v (uniform per block)
    const int nl0  = n0 & 255;

    if (type <= 1) {
        unsigned short* Dst = (type == 0) ? Qb : Kb;
        // inline RoPE: jj=c, invf=10000^(-c/16); bit-identical to the old
        // table build (__expf + sincosf, same inputs -> same outputs).
        float sn[4], cs[4];
        {
            const float invf = __expf(-(float)c * 0.5756462732485115f);
            #pragma unroll
            for (int r = 0; r < 4; ++r)
                sincosf((float)(t_base + 4 * g + r) * invf, &sn[r], &cs[r]);
        }
        #pragma unroll
        for (int tt = 0; tt < 4; ++tt) {
            const int n_l = nl0 + tt * 16;
            const int h = n_l >> 5, d = (n_l & 31) + c;
            const int bh = bn * 8 + h;
            const float sgn = (tt & 1) ? 1.f : -1.f;
            const int  ptt = tt ^ 1;
            #pragma unroll
            for (int r = 0; r < 4; ++r) {
                float v0 = acc[tt][r] + bias[tt];
                float v1 = acc[ptt][r] + bias[ptt];
                float o  = v0 * cs[r] + sgn * v1 * sn[r];
                int   t  = t_base + 4 * g + r;
                Dst[((size_t)bh * T_ + t) * D_ + d] = f2bf(o);
            }
        }
    } else {
        const int wv_ = t_base >> 5;               // s-window
        const int tw  = (t_base & 31) + 4 * g;     // t within window (4-aligned)
        // interleaved within-window position so attn reads one contiguous v8s
        const int pos0 = ((tw >> 4) & 1) * 4 + ((tw >> 2) & 3) * 8;
        #pragma unroll
        for (int tt = 0; tt < 4; ++tt) {
            const int n_l = nl0 + tt * 16;
            const int h = n_l >> 5, d = (n_l & 31) + c;
            const int bh = bn * 8 + h;
            ushort4 pk;
            pk.x = f2bf(acc[tt][0] + bias[tt]);
            pk.y = f2bf(acc[tt][1] + bias[tt]);
            pk.z = f2bf(acc[tt][2] + bias[tt]);
            pk.w = f2bf(acc[tt][3] + bias[tt]);
            *(ushort4*)(VW + (((size_t)bh * 32 + wv_) * 32 + d) * 32 + pos0) = pk;
        }
    }
}

// ---------------------------------------------------------------------------
// Kernel B: attention -- byte-verbatim R18 (131.2us chain). No LDS, no
// barriers, direct L2 reads with 1-deep register prefetch; cvtpk P-packing;
// V pre-interleaved by qkv. grid 512; block 256 (4 waves).
// ---------------------------------------------------------------------------
__global__ __launch_bounds__(256) void attn_kernel(
    const unsigned short* __restrict__ Qb,
    const unsigned short* __restrict__ Kb,
    const unsigned short* __restrict__ VW,
    unsigned short* __restrict__ Ob)
{
    const int tid  = threadIdx.x;
    const int wv   = tid >> 6;      // wave 0..3
    const int lane = tid & 63;
    const int g = lane >> 4, c = lane & 15;
    const int bx = blockIdx.x;
    const int bh = bx & 63;         // id%8 = bh%8 -> same-bh blocks same XCD
    const int k  = bx >> 6;

    const int qts[2] = { k + 8 * wv, k + 56 - 8 * wv };
    const int lim1 = qts[1] >> 1;   // j=1 is always the longer qtile

    v8s qf[2];
    #pragma unroll
    for (int j = 0; j < 2; ++j)
        qf[j] = *(const v8s*)(Qb + ((size_t)bh * T_ + qts[j] * 16 + c) * D_ + 8 * g);

    v4f o0[2], o1[2];
    float ll[2];
    #pragma unroll
    for (int j = 0; j < 2; ++j) {
        o0[j] = (v4f){0.f, 0.f, 0.f, 0.f};
        o1[j] = (v4f){0.f, 0.f, 0.f, 0.f};
        ll[j] = 0.f;
    }

    const unsigned short* Ksrc = Kb + (size_t)bh * T_ * D_;    // [t][d], 64KB
    const unsigned short* Vsrc = VW + (size_t)bh * 32 * 1024;  // [w][d][32] interleaved

    const int koff = c * 32 + 8 * g;   // K fragment
    const int voff = c * 32 + 8 * g;   // V fragment (interleaved, one v8s)

    // prefetch window 0
    v8s kA_n  = *(const v8s*)(Ksrc + koff);
    v8s kB_n  = *(const v8s*)(Ksrc + 512 + koff);
    v8s vf0_n = *(const v8s*)(Vsrc + voff);
    v8s vf1_n = *(const v8s*)(Vsrc + 512 + voff);

    for (int w = 0; w <= lim1; ++w) {
        v8s kfA = kA_n, kfB = kB_n;
        v8s vf0 = vf0_n, vf1 = vf1_n;
        if (w < lim1) {                         // wave-uniform branch
            const unsigned short* kp = Ksrc + (size_t)(w + 1) * 1024;
            const unsigned short* vp = Vsrc + (size_t)(w + 1) * 1024;
            kA_n  = *(const v8s*)(kp + koff);
            kB_n  = *(const v8s*)(kp + 512 + koff);
            vf0_n = *(const v8s*)(vp + voff);
            vf1_n = *(const v8s*)(vp + 512 + voff);
        }

        const int s0 = w * 32;
        #pragma unroll
        for (int j = 0; j < 2; ++j) {
            const int qt  = qts[j];
            const int lim = qt >> 1;
            if (lim < w) continue;          // wave-uniform
            const int q = qt * 16 + c;

            v4f zero = {0.f, 0.f, 0.f, 0.f};
            v4f sA = __builtin_amdgcn_mfma_f32_16x16x32_bf16(kfA, qf[j], zero, 0, 0, 0);
            v4f sB = __builtin_amdgcn_mfma_f32_16x16x32_bf16(kfB, qf[j], zero, 0, 0, 0);

            const bool diag = (lim == w);
            float p[8];
            #pragma unroll
            for (int r = 0; r < 4; ++r) {
                float pa = EXP2F(fmaf(sA[r], KMUL, -SHIFTL));
                float pb = EXP2F(fmaf(sB[r], KMUL, -SHIFTL));
                if (diag) {
                    if (s0 + 4 * g + r > q)      pa = 0.f;
                    if (s0 + 16 + 4 * g + r > q) pb = 0.f;
                }
                p[r] = pa; p[4 + r] = pb;
                ll[j] += pa + pb;
            }
            union { v8s v; uint4 u; } pu;
            pu.u.x = cvtpk(p[0], p[1]);
            pu.u.y = cvtpk(p[2], p[3]);
            pu.u.z = cvtpk(p[4], p[5]);
            pu.u.w = cvtpk(p[6], p[7]);
            o0[j] = __builtin_amdgcn_mfma_f32_16x16x32_bf16(pu.v, vf0, o0[j], 0, 0, 0);
            o1[j] = __builtin_amdgcn_mfma_f32_16x16x32_bf16(pu.v, vf1, o1[j], 0, 0, 0);
        }
    }

    const int bn = bh >> 3, h = bh & 7;
    #pragma unroll
    for (int j = 0; j < 2; ++j) {
        float l_s = ll[j];
        l_s += __shfl_xor(l_s, 16, 64);
        l_s += __shfl_xor(l_s, 32, 64);
        float linv = 1.0f / l_s;
        float lr[4];
        #pragma unroll
        for (int r = 0; r < 4; ++r) lr[r] = __shfl(linv, 4 * g + r, 64);
        const int q0 = qts[j] * 16;
        #pragma unroll
        for (int r = 0; r < 4; ++r) {
            unsigned short* Orow = Ob + ((size_t)bn * T_ + q0 + 4 * g + r) * E_ + h * D_;
            Orow[c]      = f2bf(o0[j][r] * lr[r]);
            Orow[16 + c] = f2bf(o1[j][r] * lr[r]);
        }
    }
}

// ---------------------------------------------------------------------------
// Kernel C: out = O @ w_proj + b_proj via MFMA, transposed fp32 store.
// R18 body; B-fragments from block-local LDS transpose of w_proj slice.
// grid (128, 4) row-fast, block 256.
// ---------------------------------------------------------------------------
__global__ __launch_bounds__(256) void proj_mfma_kernel(
    const unsigned short* __restrict__ Ob,
    const float* __restrict__ w_proj,
    const float* __restrict__ b_proj,
    float* __restrict__ out)
{
    __shared__ unsigned short WPs[64][264];   // [n_local][k] bf16, padded

    const int tid  = threadIdx.x;
    const int wsb  = tid >> 6;
    const int lane = tid & 63;
    const int g = lane >> 4, c = lane & 15;
    const int m0 = blockIdx.x * 64 + wsb * 16;
    const int n0 = blockIdx.y * 64;
    const int bn = m0 >> 10;
    const int b  = bn >> 2, nidx = bn & 3;
    const int t_base = m0 & 1023;

    // ---- per-block weight transpose: w_proj[k][n0+nl] -> WPs[nl][k] ----
    {
        const int c4 = (tid & 15) * 4;
        const int kr = tid >> 4;
        #pragma unroll
        for (int p = 0; p < 16; ++p) {
            const int k = p * 16 + kr;
            float4 w4 = *(const float4*)(w_proj + (size_t)k * E_ + n0 + c4);
            WPs[c4 + 0][k] = f2bf(w4.x);
            WPs[c4 + 1][k] = f2bf(w4.y);
            WPs[c4 + 2][k] = f2bf(w4.z);
            WPs[c4 + 3][k] = f2bf(w4.w);
        }
    }
    __syncthreads();

    const unsigned short* arow = Ob + ((size_t)bn * T_ + t_base + c) * E_;

    v4f acc[4];
    #pragma unroll
    for (int tt = 0; tt < 4; ++tt) acc[tt] = (v4f){0.f, 0.f, 0.f, 0.f};

    #pragma unroll
    for (int s = 0; s < 8; ++s) {
        v8s afrag = *(const v8s*)(arow + s * 32 + 8 * g);
        #pragma unroll
        for (int tt = 0; tt < 4; ++tt) {
            v8s bfrag = *(const v8s*)(&WPs[tt * 16 + c][s * 32 + 8 * g]);
            acc[tt] = __builtin_amdgcn_mfma_f32_16x16x32_bf16(afrag, bfrag, acc[tt], 0, 0, 0);
        }
    }

    #pragma unroll
    for (int tt = 0; tt < 4; ++tt) {
        const int n = n0 + tt * 16 + c;
        const float bp = b_proj[n];
        #pragma unroll
        for (int r = 0; r < 4; ++r) {
            const int t = t_base + 4 * g + r;
            out[((size_t)(b * T_ + t) * NB + nidx) * E_ + n] = acc[tt][r] + bp;
        }
    }
}

// ---------------------------------------------------------------------------
extern "C" void kernel_launch(void* const* d_in, const int* in_sizes, int n_in,
                              void* d_out, int out_size, void* d_ws, size_t ws_size,
                              hipStream_t stream)
{
    const float* x      = (const float*)d_in[0];
    const float* w_attn = (const float*)d_in[1];
    const float* b_attn = (const float*)d_in[2];
    const float* w_proj = (const float*)d_in[3];
    const float* b_proj = (const float*)d_in[4];
    float* out = (float*)d_out;

    // ws (ushort units): Qb/Kb/VW/Ob 2M each. (WT/WPT/tables removed, R25.)
    unsigned short* Qb  = (unsigned short*)d_ws;
    unsigned short* Kb  = Qb + 2097152;
    unsigned short* VW  = Kb + 2097152;
    unsigned short* Ob  = VW + 2097152;

    qkv_mfma_kernel<<<dim3(128, 12), 256, 0, stream>>>(x, w_attn, b_attn, Qb, Kb, VW);
    attn_kernel<<<512, 256, 0, stream>>>(Qb, Kb, VW, Ob);
    proj_mfma_kernel<<<dim3(128, 4), 256, 0, stream>>>(Ob, w_proj, b_proj, out);
}